// Round 1
// baseline (1016.105 us; speedup 1.0000x reference)
//
#include <hip/hip_runtime.h>

#define DIM 64

// ---------------- CSR construction ----------------

__global__ void hist_k(const int* __restrict__ row, int E, int* __restrict__ cnt) {
    int i = blockIdx.x * blockDim.x + threadIdx.x;
    int stride = gridDim.x * blockDim.x;
    for (; i < E; i += stride) atomicAdd(&cnt[row[i]], 1);
}

// Each block scans 2048 counts (8/thread) -> rowptr[idx+1] = inclusive-within-block,
// partial[blockIdx] = block total.
__global__ void scan1_k(const int* __restrict__ cnt, int n,
                        int* __restrict__ rowptr, int* __restrict__ partial) {
    const int CH = 8;
    int t = threadIdx.x;
    int base = blockIdx.x * (256 * CH) + t * CH;
    int v[CH];
    int run = 0;
#pragma unroll
    for (int i = 0; i < CH; i++) {
        int idx = base + i;
        int c = (idx < n) ? cnt[idx] : 0;
        run += c;
        v[i] = run;
    }
    __shared__ int sh[256];
    sh[t] = run;
    __syncthreads();
    for (int off = 1; off < 256; off <<= 1) {
        int x = (t >= off) ? sh[t - off] : 0;
        __syncthreads();
        sh[t] += x;
        __syncthreads();
    }
    int excl = sh[t] - run;
#pragma unroll
    for (int i = 0; i < CH; i++) {
        int idx = base + i;
        if (idx < n) rowptr[idx + 1] = v[i] + excl;
    }
    if (t == 255) partial[blockIdx.x] = sh[255];
}

// Single block: in-place EXCLUSIVE scan of partial[0..m), m <= 2048.
__global__ void scan2_k(int* __restrict__ partial, int m) {
    const int CH = 8;
    int t = threadIdx.x;
    int base = t * CH;
    int v[CH];
    int run = 0;
#pragma unroll
    for (int i = 0; i < CH; i++) {
        int idx = base + i;
        int c = (idx < m) ? partial[idx] : 0;
        v[i] = run;  // exclusive within thread
        run += c;
    }
    __shared__ int sh[256];
    sh[t] = run;
    __syncthreads();
    for (int off = 1; off < 256; off <<= 1) {
        int x = (t >= off) ? sh[t - off] : 0;
        __syncthreads();
        sh[t] += x;
        __syncthreads();
    }
    int excl = sh[t] - run;
#pragma unroll
    for (int i = 0; i < CH; i++) {
        int idx = base + i;
        if (idx < m) partial[idx] = v[i] + excl;
    }
}

__global__ void scan3_k(int* __restrict__ rowptr, const int* __restrict__ partial, int n) {
    int i = blockIdx.x * blockDim.x + threadIdx.x;
    if (i == 0) rowptr[0] = 0;
    if (i < n) rowptr[i + 1] += partial[i >> 11];  // 2048 elems per scan1 block
}

__global__ void scatter_k(const int* __restrict__ row, const int* __restrict__ col,
                          const float* __restrict__ vals, int E,
                          const int* __restrict__ rowptr, int* __restrict__ fill,
                          int* __restrict__ cols_s, float* __restrict__ vals_s) {
    int i = blockIdx.x * blockDim.x + threadIdx.x;
    int stride = gridDim.x * blockDim.x;
    for (; i < E; i += stride) {
        int r = row[i];
        int pos = rowptr[r] + atomicAdd(&fill[r], 1);
        cols_s[pos] = col[i];
        vals_s[pos] = vals[i];
    }
}

// ---------------- layer-1 SpMM (gather, one wave per row, lane = dim) ----------------

__global__ void spmm1_k(const float* __restrict__ emb_user, const float* __restrict__ emb_item,
                        int n_user, int n_total,
                        const int* __restrict__ rowptr, const int* __restrict__ cols_s,
                        const float* __restrict__ vals_s, float* __restrict__ e1) {
    int wave = (blockIdx.x * blockDim.x + threadIdx.x) >> 6;
    int lane = threadIdx.x & 63;
    if (wave >= n_total) return;
    int k0 = rowptr[wave], k1 = rowptr[wave + 1];
    float acc = 0.f;
    for (int k = k0; k < k1; k++) {
        int c = cols_s[k];
        float v = vals_s[k];
        const float* src = (c < n_user) ? (emb_user + (size_t)c * DIM)
                                        : (emb_item + (size_t)(c - n_user) * DIM);
        acc += v * src[lane];
    }
    e1[(size_t)wave * DIM + lane] = acc;
}

// ---------------- fused layer-2 + gather + dot epilogue ----------------
// One wave per batch element; recompute e2 rows on the fly only for the 3 needed nodes.

__global__ void final_k(const float* __restrict__ emb_user, const float* __restrict__ emb_item,
                        int n_user, const float* __restrict__ e1,
                        const int* __restrict__ rowptr, const int* __restrict__ cols_s,
                        const float* __restrict__ vals_s,
                        const int* __restrict__ u_nodes, const int* __restrict__ p_nodes,
                        const int* __restrict__ n_nodes, int B, float* __restrict__ out) {
    int wave = (blockIdx.x * blockDim.x + threadIdx.x) >> 6;
    int lane = threadIdx.x & 63;
    if (wave >= B) return;
    int nid[3] = {u_nodes[wave], p_nodes[wave], n_nodes[wave]};
    float l[3];
#pragma unroll
    for (int j = 0; j < 3; j++) {
        int r = nid[j];
        const float* base0 = (r < n_user) ? (emb_user + (size_t)r * DIM)
                                          : (emb_item + (size_t)(r - n_user) * DIM);
        float acc = base0[lane] + e1[(size_t)r * DIM + lane];  // layer0 + layer1
        int k0 = rowptr[r], k1 = rowptr[r + 1];
        float a2 = 0.f;
        for (int k = k0; k < k1; k++) {
            int c = cols_s[k];
            a2 += vals_s[k] * e1[(size_t)c * DIM + lane];  // layer2 on the fly
        }
        l[j] = (acc + a2) * (1.0f / 3.0f);
    }
    float ps = l[0] * l[1];
    float ns = l[0] * l[2];
    for (int off = 32; off; off >>= 1) {
        ps += __shfl_xor(ps, off);
        ns += __shfl_xor(ns, off);
    }
    if (lane == 0) {
        out[wave] = ps;
        out[B + wave] = ns;
    }
}

extern "C" void kernel_launch(void* const* d_in, const int* in_sizes, int n_in,
                              void* d_out, int out_size, void* d_ws, size_t ws_size,
                              hipStream_t stream) {
    const float* emb_user = (const float*)d_in[0];
    const float* emb_item = (const float*)d_in[1];
    const float* gvals    = (const float*)d_in[2];
    const int*   grow     = (const int*)d_in[3];
    const int*   gcol     = (const int*)d_in[4];
    const int*   unodes   = (const int*)d_in[5];
    const int*   pnodes   = (const int*)d_in[6];
    const int*   nnodes   = (const int*)d_in[7];
    float* out = (float*)d_out;

    int n_user = in_sizes[0] / DIM;
    int n_item = in_sizes[1] / DIM;
    int N = n_user + n_item;
    int E = in_sizes[2];
    int B = in_sizes[5];

    char* ws = (char*)d_ws;
    size_t off = 0;
    auto alloc = [&](size_t bytes) -> void* {
        void* p = ws + off;
        off = (off + bytes + 255) & ~(size_t)255;
        return p;
    };
    int*   rowptr  = (int*)alloc((size_t)(N + 1) * 4);
    int*   cnt     = (int*)alloc((size_t)N * 4);       // reused as fill counters
    int*   partial = (int*)alloc(2048 * 4);
    int*   cols_s  = (int*)alloc((size_t)E * 4);
    float* vals_s  = (float*)alloc((size_t)E * 4);
    float* e1      = (float*)alloc((size_t)N * DIM * 4);
    (void)ws_size; (void)n_in; (void)out_size;

    // CSR build
    hipMemsetAsync(cnt, 0, (size_t)N * 4, stream);
    hist_k<<<4096, 256, 0, stream>>>(grow, E, cnt);
    int nb1 = (N + 2047) / 2048;
    scan1_k<<<nb1, 256, 0, stream>>>(cnt, N, rowptr, partial);
    scan2_k<<<1, 256, 0, stream>>>(partial, nb1);
    scan3_k<<<(N + 255) / 256, 256, 0, stream>>>(rowptr, partial, N);
    hipMemsetAsync(cnt, 0, (size_t)N * 4, stream);
    scatter_k<<<4096, 256, 0, stream>>>(grow, gcol, gvals, E, rowptr, cnt, cols_s, vals_s);

    // layer-1 SpMM over all rows
    spmm1_k<<<(N + 3) / 4, 256, 0, stream>>>(emb_user, emb_item, n_user, N,
                                             rowptr, cols_s, vals_s, e1);
    // fused layer-2 + gather + dots
    final_k<<<(B + 3) / 4, 256, 0, stream>>>(emb_user, emb_item, n_user, e1,
                                             rowptr, cols_s, vals_s,
                                             unodes, pnodes, nnodes, B, out);
}

// Round 2
// 955.420 us; speedup vs baseline: 1.0635x; 1.0635x over previous
//
#include <hip/hip_runtime.h>

#define DIM 64

__device__ __forceinline__ float bf2f(unsigned short h) {
    return __uint_as_float(((unsigned int)h) << 16);
}
__device__ __forceinline__ unsigned short f2bf(float f) {
    unsigned int u = __float_as_uint(f);
    return (unsigned short)((u + 0x7FFFu + ((u >> 16) & 1u)) >> 16);  // round-to-nearest-even
}

// ---------------- f32 -> packed bf16 conversion (streaming) ----------------

__global__ void conv_k(const float* __restrict__ a, int n, unsigned short* __restrict__ o) {
    int i = blockIdx.x * blockDim.x + threadIdx.x;
    int stride = gridDim.x * blockDim.x;
    int n8 = n >> 3;
    for (int t = i; t < n8; t += stride) {
        const float4* p = (const float4*)(a + (size_t)t * 8);
        float4 x = p[0], y = p[1];
        uint4 v;
        v.x = (unsigned)f2bf(x.x) | ((unsigned)f2bf(x.y) << 16);
        v.y = (unsigned)f2bf(x.z) | ((unsigned)f2bf(x.w) << 16);
        v.z = (unsigned)f2bf(y.x) | ((unsigned)f2bf(y.y) << 16);
        v.w = (unsigned)f2bf(y.z) | ((unsigned)f2bf(y.w) << 16);
        ((uint4*)o)[t] = v;
    }
    for (int t = n8 * 8 + i; t < n; t += stride) o[t] = f2bf(a[t]);
}

// ---------------- CSR construction ----------------

__global__ void hist_k(const int* __restrict__ row, int E, int* __restrict__ cnt) {
    int i = blockIdx.x * blockDim.x + threadIdx.x;
    int stride = gridDim.x * blockDim.x;
    int E4 = E >> 2;
    for (int t = i; t < E4; t += stride) {
        int4 r = ((const int4*)row)[t];
        atomicAdd(&cnt[r.x], 1);
        atomicAdd(&cnt[r.y], 1);
        atomicAdd(&cnt[r.z], 1);
        atomicAdd(&cnt[r.w], 1);
    }
    for (int t = E4 * 4 + i; t < E; t += stride) atomicAdd(&cnt[row[t]], 1);
}

__global__ void scan1_k(const int* __restrict__ cnt, int n,
                        int* __restrict__ rowptr, int* __restrict__ partial) {
    const int CH = 8;
    int t = threadIdx.x;
    int base = blockIdx.x * (256 * CH) + t * CH;
    int v[CH];
    int run = 0;
#pragma unroll
    for (int i = 0; i < CH; i++) {
        int idx = base + i;
        int c = (idx < n) ? cnt[idx] : 0;
        run += c;
        v[i] = run;
    }
    __shared__ int sh[256];
    sh[t] = run;
    __syncthreads();
    for (int off = 1; off < 256; off <<= 1) {
        int x = (t >= off) ? sh[t - off] : 0;
        __syncthreads();
        sh[t] += x;
        __syncthreads();
    }
    int excl = sh[t] - run;
#pragma unroll
    for (int i = 0; i < CH; i++) {
        int idx = base + i;
        if (idx < n) rowptr[idx + 1] = v[i] + excl;
    }
    if (t == 255) partial[blockIdx.x] = sh[255];
}

__global__ void scan2_k(int* __restrict__ partial, int m) {
    const int CH = 8;
    int t = threadIdx.x;
    int base = t * CH;
    int v[CH];
    int run = 0;
#pragma unroll
    for (int i = 0; i < CH; i++) {
        int idx = base + i;
        int c = (idx < m) ? partial[idx] : 0;
        v[i] = run;
        run += c;
    }
    __shared__ int sh[256];
    sh[t] = run;
    __syncthreads();
    for (int off = 1; off < 256; off <<= 1) {
        int x = (t >= off) ? sh[t - off] : 0;
        __syncthreads();
        sh[t] += x;
        __syncthreads();
    }
    int excl = sh[t] - run;
#pragma unroll
    for (int i = 0; i < CH; i++) {
        int idx = base + i;
        if (idx < m) partial[idx] = v[i] + excl;
    }
}

__global__ void scan3_k(int* __restrict__ rowptr, const int* __restrict__ partial, int n) {
    int i = blockIdx.x * blockDim.x + threadIdx.x;
    if (i == 0) rowptr[0] = 0;
    if (i < n) rowptr[i + 1] += partial[i >> 11];
}

__global__ void scatter_k(const int* __restrict__ row, const int* __restrict__ col,
                          const float* __restrict__ vals, int E,
                          int* __restrict__ fill, int2* __restrict__ pairs) {
    int i = blockIdx.x * blockDim.x + threadIdx.x;
    int stride = gridDim.x * blockDim.x;
    int E4 = E >> 2;
    for (int t = i; t < E4; t += stride) {
        int4 r = ((const int4*)row)[t];
        int4 c = ((const int4*)col)[t];
        float4 v = ((const float4*)vals)[t];
        int p0 = atomicAdd(&fill[r.x], 1);
        pairs[p0] = make_int2(c.x, __float_as_int(v.x));
        int p1 = atomicAdd(&fill[r.y], 1);
        pairs[p1] = make_int2(c.y, __float_as_int(v.y));
        int p2 = atomicAdd(&fill[r.z], 1);
        pairs[p2] = make_int2(c.z, __float_as_int(v.z));
        int p3 = atomicAdd(&fill[r.w], 1);
        pairs[p3] = make_int2(c.w, __float_as_int(v.w));
    }
    for (int t = E4 * 4 + i; t < E; t += stride) {
        int p = atomicAdd(&fill[row[t]], 1);
        pairs[p] = make_int2(col[t], __float_as_int(vals[t]));
    }
}

// ---------------- layer-1 SpMM: wave per row, lane = dim, 8-wide ILP ----------------

__global__ void spmm1_k(const unsigned short* __restrict__ emb16,
                        const int* __restrict__ rowptr, const int2* __restrict__ pairs,
                        int n_total, unsigned short* __restrict__ e1) {
    int wave = (blockIdx.x * blockDim.x + threadIdx.x) >> 6;
    int lane = threadIdx.x & 63;
    if (wave >= n_total) return;
    int k0 = rowptr[wave], k1 = rowptr[wave + 1];
    float acc0 = 0.f, acc1 = 0.f;
    for (int k = k0; k < k1; k += 8) {
#pragma unroll
        for (int j = 0; j < 8; j++) {
            int kk = k + j;
            int kc = kk < k1 ? kk : k1 - 1;      // clamp: loads always valid, no branch
            int2 p = pairs[kc];
            float v = kk < k1 ? __int_as_float(p.y) : 0.f;
            float x = v * bf2f(emb16[(size_t)p.x * DIM + lane]);
            if (j & 1) acc1 += x; else acc0 += x;
        }
    }
    e1[(size_t)wave * DIM + lane] = f2bf(acc0 + acc1);
}

// ---------------- fused layer-2 + gather + dot epilogue ----------------

__global__ void final_k(const float* __restrict__ emb_user, const float* __restrict__ emb_item,
                        int n_user, const unsigned short* __restrict__ e1,
                        const int* __restrict__ rowptr, const int2* __restrict__ pairs,
                        const int* __restrict__ u_nodes, const int* __restrict__ p_nodes,
                        const int* __restrict__ n_nodes, int B, float* __restrict__ out) {
    int wave = (blockIdx.x * blockDim.x + threadIdx.x) >> 6;
    int lane = threadIdx.x & 63;
    if (wave >= B) return;
    int nid[3] = {u_nodes[wave], p_nodes[wave], n_nodes[wave]};
    float l[3];
#pragma unroll
    for (int j = 0; j < 3; j++) {
        int r = nid[j];
        const float* base0 = (r < n_user) ? (emb_user + (size_t)r * DIM)
                                          : (emb_item + (size_t)(r - n_user) * DIM);
        float acc = base0[lane] + bf2f(e1[(size_t)r * DIM + lane]);  // layer0(f32) + layer1
        int k0 = rowptr[r], k1 = rowptr[r + 1];
        float a20 = 0.f, a21 = 0.f;
        for (int k = k0; k < k1; k += 8) {
#pragma unroll
            for (int jj = 0; jj < 8; jj++) {
                int kk = k + jj;
                int kc = kk < k1 ? kk : k1 - 1;
                int2 p = pairs[kc];
                float v = kk < k1 ? __int_as_float(p.y) : 0.f;
                float x = v * bf2f(e1[(size_t)p.x * DIM + lane]);
                if (jj & 1) a21 += x; else a20 += x;
            }
        }
        l[j] = (acc + a20 + a21) * (1.0f / 3.0f);
    }
    float ps = l[0] * l[1];
    float ns = l[0] * l[2];
    for (int off = 32; off; off >>= 1) {
        ps += __shfl_xor(ps, off);
        ns += __shfl_xor(ns, off);
    }
    if (lane == 0) {
        out[wave] = ps;
        out[B + wave] = ns;
    }
}

extern "C" void kernel_launch(void* const* d_in, const int* in_sizes, int n_in,
                              void* d_out, int out_size, void* d_ws, size_t ws_size,
                              hipStream_t stream) {
    const float* emb_user = (const float*)d_in[0];
    const float* emb_item = (const float*)d_in[1];
    const float* gvals    = (const float*)d_in[2];
    const int*   grow     = (const int*)d_in[3];
    const int*   gcol     = (const int*)d_in[4];
    const int*   unodes   = (const int*)d_in[5];
    const int*   pnodes   = (const int*)d_in[6];
    const int*   nnodes   = (const int*)d_in[7];
    float* out = (float*)d_out;

    int n_user = in_sizes[0] / DIM;
    int n_item = in_sizes[1] / DIM;
    int N = n_user + n_item;
    int E = in_sizes[2];
    int B = in_sizes[5];

    char* ws = (char*)d_ws;
    size_t off = 0;
    auto alloc = [&](size_t bytes) -> void* {
        void* p = ws + off;
        off = (off + bytes + 255) & ~(size_t)255;
        return p;
    };
    int*            rowptr  = (int*)alloc((size_t)(N + 1) * 4);
    int*            cnt     = (int*)alloc((size_t)N * 4);   // hist counts, then fill cursors
    int*            partial = (int*)alloc(2048 * 4);
    int2*           pairs   = (int2*)alloc((size_t)E * 8);
    unsigned short* emb16   = (unsigned short*)alloc((size_t)N * DIM * 2);
    unsigned short* e1      = (unsigned short*)alloc((size_t)N * DIM * 2);
    (void)ws_size; (void)n_in; (void)out_size;

    // bf16 pack of embeddings (independent of CSR chain)
    conv_k<<<2048, 256, 0, stream>>>(emb_user, n_user * DIM, emb16);
    conv_k<<<2048, 256, 0, stream>>>(emb_item, n_item * DIM, emb16 + (size_t)n_user * DIM);

    // CSR build
    hipMemsetAsync(cnt, 0, (size_t)N * 4, stream);
    hist_k<<<2048, 256, 0, stream>>>(grow, E, cnt);
    int nb1 = (N + 2047) / 2048;
    scan1_k<<<nb1, 256, 0, stream>>>(cnt, N, rowptr, partial);
    scan2_k<<<1, 256, 0, stream>>>(partial, nb1);
    scan3_k<<<(N + 255) / 256, 256, 0, stream>>>(rowptr, partial, N);
    hipMemcpyAsync(cnt, rowptr, (size_t)N * 4, hipMemcpyDeviceToDevice, stream);
    scatter_k<<<2048, 256, 0, stream>>>(grow, gcol, gvals, E, cnt, pairs);

    // layer-1 SpMM over all rows
    spmm1_k<<<(N + 3) / 4, 256, 0, stream>>>(emb16, rowptr, pairs, N, e1);
    // fused layer-2 + gather + dots
    final_k<<<(B + 3) / 4, 256, 0, stream>>>(emb_user, emb_item, n_user, e1,
                                             rowptr, pairs,
                                             unodes, pnodes, nnodes, B, out);
}

// Round 3
// 540.092 us; speedup vs baseline: 1.8814x; 1.7690x over previous
//
#include <hip/hip_runtime.h>

#define DIM 64
#define CHUNK 4096   // edges per partition block
#define MAXNB 2048   // max coarse buckets (supports N <= 524288, NBLK <= 2048)

__device__ __forceinline__ float bf2f(unsigned short h) {
    return __uint_as_float(((unsigned int)h) << 16);
}
__device__ __forceinline__ unsigned short f2bf(float f) {
    unsigned int u = __float_as_uint(f);
    return (unsigned short)((u + 0x7FFFu + ((u >> 16) & 1u)) >> 16);  // RNE
}

// inclusive block scan over 256 per-thread values; sh[255] = total after call
__device__ __forceinline__ int blockScan256(int v, int* sh) {
    int t = threadIdx.x;
    sh[t] = v;
    __syncthreads();
    for (int off = 1; off < 256; off <<= 1) {
        int x = (t >= off) ? sh[t - off] : 0;
        __syncthreads();
        sh[t] += x;
        __syncthreads();
    }
    return sh[t];
}

// ---------------- f32 -> packed bf16 conversion (streaming) ----------------

__global__ void conv_k(const float* __restrict__ a, int n, unsigned short* __restrict__ o) {
    int i = blockIdx.x * blockDim.x + threadIdx.x;
    int stride = gridDim.x * blockDim.x;
    int n8 = n >> 3;
    for (int t = i; t < n8; t += stride) {
        const float4* p = (const float4*)(a + (size_t)t * 8);
        float4 x = p[0], y = p[1];
        uint4 v;
        v.x = (unsigned)f2bf(x.x) | ((unsigned)f2bf(x.y) << 16);
        v.y = (unsigned)f2bf(x.z) | ((unsigned)f2bf(x.w) << 16);
        v.z = (unsigned)f2bf(y.x) | ((unsigned)f2bf(y.y) << 16);
        v.w = (unsigned)f2bf(y.z) | ((unsigned)f2bf(y.w) << 16);
        ((uint4*)o)[t] = v;
    }
    for (int t = n8 * 8 + i; t < n; t += stride) o[t] = f2bf(a[t]);
}

// ---------------- two-level counting sort (no global atomics) ----------------

// P1a: per-chunk LDS histogram of coarse buckets (row>>8) -> counts[blk][b] (coalesced)
__global__ void p1a_hist(const int* __restrict__ row, int E, int NB,
                         int* __restrict__ counts) {
    __shared__ int h[MAXNB];
    for (int b = threadIdx.x; b < NB; b += 256) h[b] = 0;
    __syncthreads();
    int base = blockIdx.x * CHUNK;
    int end = min(base + CHUNK, E);
    int vend = base + ((end - base) & ~3);
    for (int i = base + threadIdx.x * 4; i < vend; i += 1024) {
        int4 r = *(const int4*)(row + i);
        atomicAdd(&h[r.x >> 8], 1);
        atomicAdd(&h[r.y >> 8], 1);
        atomicAdd(&h[r.z >> 8], 1);
        atomicAdd(&h[r.w >> 8], 1);
    }
    for (int i = vend + threadIdx.x; i < end; i += 256) atomicAdd(&h[row[i] >> 8], 1);
    __syncthreads();
    int blk = blockIdx.x;
    for (int b = threadIdx.x; b < NB; b += 256) counts[(size_t)blk * NB + b] = h[b];
}

// P1b: per-bucket column exclusive scan over blocks (in place); bucketTotal[b] = column sum
__global__ void p1b_scan(int* __restrict__ counts, int NBLK, int NB,
                         int* __restrict__ bucketTotal) {
    int b = blockIdx.x, t = threadIdx.x;
    __shared__ int sh[256];
    int v[8];
    int run = 0;
#pragma unroll
    for (int i = 0; i < 8; i++) {
        int idx = t * 8 + i;
        int c = (idx < NBLK) ? counts[(size_t)idx * NB + b] : 0;
        v[i] = run;           // exclusive within thread
        run += c;
    }
    int inc = blockScan256(run, sh);
    int excl = inc - run;
#pragma unroll
    for (int i = 0; i < 8; i++) {
        int idx = t * 8 + i;
        if (idx < NBLK) counts[(size_t)idx * NB + b] = v[i] + excl;
    }
    if (t == 255) bucketTotal[b] = sh[255];
}

// exclusive scan of bucketTotal[0..NB) -> bucketStart[0..NB]
__global__ void p_scan_tot(const int* __restrict__ bucketTotal, int NB,
                           int* __restrict__ bucketStart) {
    int t = threadIdx.x;
    __shared__ int sh[256];
    int v[8];
    int run = 0;
#pragma unroll
    for (int i = 0; i < 8; i++) {
        int idx = t * 8 + i;
        int c = (idx < NB) ? bucketTotal[idx] : 0;
        v[i] = run;
        run += c;
    }
    int inc = blockScan256(run, sh);
    int excl = inc - run;
#pragma unroll
    for (int i = 0; i < 8; i++) {
        int idx = t * 8 + i;
        if (idx < NB) bucketStart[idx] = v[i] + excl;
    }
    if (t == 255) bucketStart[NB] = sh[255];
}

// P1c: scatter edges into bucket-grouped bdata via LDS cursors
__global__ void p1c_scatter(const int* __restrict__ row, const int* __restrict__ col,
                            const float* __restrict__ vals, int E, int NB,
                            const int* __restrict__ counts, const int* __restrict__ bucketStart,
                            int2* __restrict__ bdata) {
    __shared__ int cur[MAXNB];
    int blk = blockIdx.x;
    for (int b = threadIdx.x; b < NB; b += 256)
        cur[b] = bucketStart[b] + counts[(size_t)blk * NB + b];
    __syncthreads();
    int base = blk * CHUNK;
    int end = min(base + CHUNK, E);
    int vend = base + ((end - base) & ~3);
    for (int i = base + threadIdx.x * 4; i < vend; i += 1024) {
        int4 r = *(const int4*)(row + i);
        int4 c = *(const int4*)(col + i);
        float4 v = *(const float4*)(vals + i);
        int p0 = atomicAdd(&cur[r.x >> 8], 1);
        bdata[p0] = make_int2(((r.x & 255) << 20) | c.x, __float_as_int(v.x));
        int p1 = atomicAdd(&cur[r.y >> 8], 1);
        bdata[p1] = make_int2(((r.y & 255) << 20) | c.y, __float_as_int(v.y));
        int p2 = atomicAdd(&cur[r.z >> 8], 1);
        bdata[p2] = make_int2(((r.z & 255) << 20) | c.z, __float_as_int(v.z));
        int p3 = atomicAdd(&cur[r.w >> 8], 1);
        bdata[p3] = make_int2(((r.w & 255) << 20) | c.w, __float_as_int(v.w));
    }
    for (int i = vend + threadIdx.x; i < end; i += 256) {
        int r = row[i];
        int p = atomicAdd(&cur[r >> 8], 1);
        bdata[p] = make_int2(((r & 255) << 20) | col[i], __float_as_int(vals[i]));
    }
}

// P2: per-bucket regroup by exact row (LDS hist + scan + cursors); emits rowptr + pairs
__global__ void p2_group(const int2* __restrict__ bdata, const int* __restrict__ bucketStart,
                         int NB, int N, int E,
                         int* __restrict__ rowptr, int2* __restrict__ pairs) {
    __shared__ int hist[256];
    __shared__ int sh[256];
    __shared__ int cur[256];
    int b = blockIdx.x, t = threadIdx.x;
    int s0 = bucketStart[b], s1 = bucketStart[b + 1];
    hist[t] = 0;
    __syncthreads();
    for (int i = s0 + t; i < s1; i += 256)
        atomicAdd(&hist[(bdata[i].x >> 20) & 255], 1);
    __syncthreads();
    int h = hist[t];
    int inc = blockScan256(h, sh);
    int excl = inc - h;
    int r = b * 256 + t;
    if (r < N) rowptr[r] = s0 + excl;
    cur[t] = excl;
    __syncthreads();
    for (int i = s0 + t; i < s1; i += 256) {
        int2 e = bdata[i];
        int rl = (e.x >> 20) & 255;
        int pos = atomicAdd(&cur[rl], 1);
        pairs[(size_t)s0 + pos] = make_int2(e.x & 0xFFFFF, e.y);
    }
    if (b == NB - 1 && t == 0) rowptr[N] = E;
}

// ---------------- layer-1 SpMM: wave per row, lane = dim, 8-wide ILP ----------------

__global__ void spmm1_k(const unsigned short* __restrict__ emb16,
                        const int* __restrict__ rowptr, const int2* __restrict__ pairs,
                        int n_total, unsigned short* __restrict__ e1) {
    int wave = (blockIdx.x * blockDim.x + threadIdx.x) >> 6;
    int lane = threadIdx.x & 63;
    if (wave >= n_total) return;
    int k0 = rowptr[wave], k1 = rowptr[wave + 1];
    float acc0 = 0.f, acc1 = 0.f;
    for (int k = k0; k < k1; k += 8) {
#pragma unroll
        for (int j = 0; j < 8; j++) {
            int kk = k + j;
            int kc = kk < k1 ? kk : k1 - 1;
            int2 p = pairs[kc];
            float v = kk < k1 ? __int_as_float(p.y) : 0.f;
            float x = v * bf2f(emb16[(size_t)p.x * DIM + lane]);
            if (j & 1) acc1 += x; else acc0 += x;
        }
    }
    e1[(size_t)wave * DIM + lane] = f2bf(acc0 + acc1);
}

// ---------------- fused layer-2 + gather + dot epilogue ----------------

__global__ void final_k(const float* __restrict__ emb_user, const float* __restrict__ emb_item,
                        int n_user, const unsigned short* __restrict__ e1,
                        const int* __restrict__ rowptr, const int2* __restrict__ pairs,
                        const int* __restrict__ u_nodes, const int* __restrict__ p_nodes,
                        const int* __restrict__ n_nodes, int B, float* __restrict__ out) {
    int wave = (blockIdx.x * blockDim.x + threadIdx.x) >> 6;
    int lane = threadIdx.x & 63;
    if (wave >= B) return;
    int nid[3] = {u_nodes[wave], p_nodes[wave], n_nodes[wave]};
    float l[3];
#pragma unroll
    for (int j = 0; j < 3; j++) {
        int r = nid[j];
        const float* base0 = (r < n_user) ? (emb_user + (size_t)r * DIM)
                                          : (emb_item + (size_t)(r - n_user) * DIM);
        float acc = base0[lane] + bf2f(e1[(size_t)r * DIM + lane]);
        int k0 = rowptr[r], k1 = rowptr[r + 1];
        float a20 = 0.f, a21 = 0.f;
        for (int k = k0; k < k1; k += 8) {
#pragma unroll
            for (int jj = 0; jj < 8; jj++) {
                int kk = k + jj;
                int kc = kk < k1 ? kk : k1 - 1;
                int2 p = pairs[kc];
                float v = kk < k1 ? __int_as_float(p.y) : 0.f;
                float x = v * bf2f(e1[(size_t)p.x * DIM + lane]);
                if (jj & 1) a21 += x; else a20 += x;
            }
        }
        l[j] = (acc + a20 + a21) * (1.0f / 3.0f);
    }
    float ps = l[0] * l[1];
    float ns = l[0] * l[2];
    for (int off = 32; off; off >>= 1) {
        ps += __shfl_xor(ps, off);
        ns += __shfl_xor(ns, off);
    }
    if (lane == 0) {
        out[wave] = ps;
        out[B + wave] = ns;
    }
}

extern "C" void kernel_launch(void* const* d_in, const int* in_sizes, int n_in,
                              void* d_out, int out_size, void* d_ws, size_t ws_size,
                              hipStream_t stream) {
    const float* emb_user = (const float*)d_in[0];
    const float* emb_item = (const float*)d_in[1];
    const float* gvals    = (const float*)d_in[2];
    const int*   grow     = (const int*)d_in[3];
    const int*   gcol     = (const int*)d_in[4];
    const int*   unodes   = (const int*)d_in[5];
    const int*   pnodes   = (const int*)d_in[6];
    const int*   nnodes   = (const int*)d_in[7];
    float* out = (float*)d_out;

    int n_user = in_sizes[0] / DIM;
    int n_item = in_sizes[1] / DIM;
    int N = n_user + n_item;
    int E = in_sizes[2];
    int B = in_sizes[5];
    int NB = (N + 255) >> 8;               // coarse buckets (row>>8)
    int NBLK = (E + CHUNK - 1) / CHUNK;    // partition blocks

    char* ws = (char*)d_ws;
    size_t off = 0;
    auto alloc = [&](size_t bytes) -> void* {
        void* p = ws + off;
        off = (off + bytes + 255) & ~(size_t)255;
        return p;
    };
    int*  rowptr      = (int*)alloc((size_t)(N + 1) * 4);
    int*  bucketTotal = (int*)alloc((size_t)MAXNB * 4);
    int*  bucketStart = (int*)alloc((size_t)(MAXNB + 1) * 4);
    int2* pairs       = (int2*)alloc((size_t)E * 8);
    // regionB: bdata (dead after P2) shares with emb16 (written after P2)
    char* regionB = (char*)alloc((size_t)E * 8 > (size_t)N * DIM * 2 ? (size_t)E * 8
                                                                     : (size_t)N * DIM * 2);
    int2*           bdata = (int2*)regionB;
    unsigned short* emb16 = (unsigned short*)regionB;
    // regionA: counts (dead after P1c) shares with e1 (written by spmm1)
    size_t countsBytes = (size_t)NBLK * NB * 4;
    size_t e1Bytes = (size_t)N * DIM * 2;
    char* regionA = (char*)alloc(countsBytes > e1Bytes ? countsBytes : e1Bytes);
    int*            counts = (int*)regionA;
    unsigned short* e1     = (unsigned short*)regionA;
    (void)ws_size; (void)n_in; (void)out_size;

    // CSR build via two-level counting sort (no global atomics)
    p1a_hist<<<NBLK, 256, 0, stream>>>(grow, E, NB, counts);
    p1b_scan<<<NB, 256, 0, stream>>>(counts, NBLK, NB, bucketTotal);
    p_scan_tot<<<1, 256, 0, stream>>>(bucketTotal, NB, bucketStart);
    p1c_scatter<<<NBLK, 256, 0, stream>>>(grow, gcol, gvals, E, NB, counts, bucketStart, bdata);
    p2_group<<<NB, 256, 0, stream>>>(bdata, bucketStart, NB, N, E, rowptr, pairs);

    // bf16 pack of embeddings (after P2: emb16 overlays bdata)
    conv_k<<<2048, 256, 0, stream>>>(emb_user, n_user * DIM, emb16);
    conv_k<<<2048, 256, 0, stream>>>(emb_item, n_item * DIM, emb16 + (size_t)n_user * DIM);

    // layer-1 SpMM over all rows (e1 overlays dead counts)
    spmm1_k<<<(N + 3) / 4, 256, 0, stream>>>(emb16, rowptr, pairs, N, e1);
    // fused layer-2 + gather + dots
    final_k<<<(B + 3) / 4, 256, 0, stream>>>(emb_user, emb_item, n_user, e1,
                                             rowptr, pairs,
                                             unodes, pnodes, nnodes, B, out);
}

// Round 4
// 320.240 us; speedup vs baseline: 3.1730x; 1.6865x over previous
//
#include <hip/hip_runtime.h>

#define DIM 64
#define CHUNK 4096   // edges per partition block
#define MAXNB 2048   // max coarse buckets (supports N <= 524288, NBLK <= 2048)

__device__ __forceinline__ float bf2f(unsigned short h) {
    return __uint_as_float(((unsigned int)h) << 16);
}
__device__ __forceinline__ unsigned short f2bf(float f) {
    unsigned int u = __float_as_uint(f);
    return (unsigned short)((u + 0x7FFFu + ((u >> 16) & 1u)) >> 16);  // RNE
}
__device__ __forceinline__ float4 bf2f4(uint2 g) {
    float4 x;
    x.x = __uint_as_float(g.x << 16);
    x.y = __uint_as_float(g.x & 0xffff0000u);
    x.z = __uint_as_float(g.y << 16);
    x.w = __uint_as_float(g.y & 0xffff0000u);
    return x;
}

// inclusive block scan over 256 per-thread values; sh[255] = total after call
__device__ __forceinline__ int blockScan256(int v, int* sh) {
    int t = threadIdx.x;
    sh[t] = v;
    __syncthreads();
    for (int off = 1; off < 256; off <<= 1) {
        int x = (t >= off) ? sh[t - off] : 0;
        __syncthreads();
        sh[t] += x;
        __syncthreads();
    }
    return sh[t];
}

// ---------------- f32 -> packed bf16 conversion (streaming) ----------------

__global__ void conv_k(const float* __restrict__ a, int n, unsigned short* __restrict__ o) {
    int i = blockIdx.x * blockDim.x + threadIdx.x;
    int stride = gridDim.x * blockDim.x;
    int n8 = n >> 3;
    for (int t = i; t < n8; t += stride) {
        const float4* p = (const float4*)(a + (size_t)t * 8);
        float4 x = p[0], y = p[1];
        uint4 v;
        v.x = (unsigned)f2bf(x.x) | ((unsigned)f2bf(x.y) << 16);
        v.y = (unsigned)f2bf(x.z) | ((unsigned)f2bf(x.w) << 16);
        v.z = (unsigned)f2bf(y.x) | ((unsigned)f2bf(y.y) << 16);
        v.w = (unsigned)f2bf(y.z) | ((unsigned)f2bf(y.w) << 16);
        ((uint4*)o)[t] = v;
    }
    for (int t = n8 * 8 + i; t < n; t += stride) o[t] = f2bf(a[t]);
}

// ---------------- two-level counting sort (no global atomics) ----------------

__global__ void p1a_hist(const int* __restrict__ row, int E, int NB,
                         int* __restrict__ counts) {
    __shared__ int h[MAXNB];
    for (int b = threadIdx.x; b < NB; b += 256) h[b] = 0;
    __syncthreads();
    int base = blockIdx.x * CHUNK;
    int end = min(base + CHUNK, E);
    int vend = base + ((end - base) & ~3);
    for (int i = base + threadIdx.x * 4; i < vend; i += 1024) {
        int4 r = *(const int4*)(row + i);
        atomicAdd(&h[r.x >> 8], 1);
        atomicAdd(&h[r.y >> 8], 1);
        atomicAdd(&h[r.z >> 8], 1);
        atomicAdd(&h[r.w >> 8], 1);
    }
    for (int i = vend + threadIdx.x; i < end; i += 256) atomicAdd(&h[row[i] >> 8], 1);
    __syncthreads();
    int blk = blockIdx.x;
    for (int b = threadIdx.x; b < NB; b += 256) counts[(size_t)blk * NB + b] = h[b];
}

__global__ void p1b_scan(int* __restrict__ counts, int NBLK, int NB,
                         int* __restrict__ bucketTotal) {
    int b = blockIdx.x, t = threadIdx.x;
    __shared__ int sh[256];
    int v[8];
    int run = 0;
#pragma unroll
    for (int i = 0; i < 8; i++) {
        int idx = t * 8 + i;
        int c = (idx < NBLK) ? counts[(size_t)idx * NB + b] : 0;
        v[i] = run;           // exclusive within thread
        run += c;
    }
    int inc = blockScan256(run, sh);
    int excl = inc - run;
#pragma unroll
    for (int i = 0; i < 8; i++) {
        int idx = t * 8 + i;
        if (idx < NBLK) counts[(size_t)idx * NB + b] = v[i] + excl;
    }
    if (t == 255) bucketTotal[b] = sh[255];
}

__global__ void p_scan_tot(const int* __restrict__ bucketTotal, int NB,
                           int* __restrict__ bucketStart) {
    int t = threadIdx.x;
    __shared__ int sh[256];
    int v[8];
    int run = 0;
#pragma unroll
    for (int i = 0; i < 8; i++) {
        int idx = t * 8 + i;
        int c = (idx < NB) ? bucketTotal[idx] : 0;
        v[i] = run;
        run += c;
    }
    int inc = blockScan256(run, sh);
    int excl = inc - run;
#pragma unroll
    for (int i = 0; i < 8; i++) {
        int idx = t * 8 + i;
        if (idx < NB) bucketStart[idx] = v[i] + excl;
    }
    if (t == 255) bucketStart[NB] = sh[255];
}

__global__ void p1c_scatter(const int* __restrict__ row, const int* __restrict__ col,
                            const float* __restrict__ vals, int E, int NB,
                            const int* __restrict__ counts, const int* __restrict__ bucketStart,
                            int2* __restrict__ bdata) {
    __shared__ int cur[MAXNB];
    int blk = blockIdx.x;
    for (int b = threadIdx.x; b < NB; b += 256)
        cur[b] = bucketStart[b] + counts[(size_t)blk * NB + b];
    __syncthreads();
    int base = blk * CHUNK;
    int end = min(base + CHUNK, E);
    int vend = base + ((end - base) & ~3);
    for (int i = base + threadIdx.x * 4; i < vend; i += 1024) {
        int4 r = *(const int4*)(row + i);
        int4 c = *(const int4*)(col + i);
        float4 v = *(const float4*)(vals + i);
        int p0 = atomicAdd(&cur[r.x >> 8], 1);
        bdata[p0] = make_int2(((r.x & 255) << 20) | c.x, __float_as_int(v.x));
        int p1 = atomicAdd(&cur[r.y >> 8], 1);
        bdata[p1] = make_int2(((r.y & 255) << 20) | c.y, __float_as_int(v.y));
        int p2 = atomicAdd(&cur[r.z >> 8], 1);
        bdata[p2] = make_int2(((r.z & 255) << 20) | c.z, __float_as_int(v.z));
        int p3 = atomicAdd(&cur[r.w >> 8], 1);
        bdata[p3] = make_int2(((r.w & 255) << 20) | c.w, __float_as_int(v.w));
    }
    for (int i = vend + threadIdx.x; i < end; i += 256) {
        int r = row[i];
        int p = atomicAdd(&cur[r >> 8], 1);
        bdata[p] = make_int2(((r & 255) << 20) | col[i], __float_as_int(vals[i]));
    }
}

__global__ void p2_group(const int2* __restrict__ bdata, const int* __restrict__ bucketStart,
                         int NB, int N, int E,
                         int* __restrict__ rowptr, int2* __restrict__ pairs) {
    __shared__ int hist[256];
    __shared__ int sh[256];
    __shared__ int cur[256];
    int b = blockIdx.x, t = threadIdx.x;
    int s0 = bucketStart[b], s1 = bucketStart[b + 1];
    hist[t] = 0;
    __syncthreads();
    for (int i = s0 + t; i < s1; i += 256)
        atomicAdd(&hist[(bdata[i].x >> 20) & 255], 1);
    __syncthreads();
    int h = hist[t];
    int inc = blockScan256(h, sh);
    int excl = inc - h;
    int r = b * 256 + t;
    if (r < N) rowptr[r] = s0 + excl;
    cur[t] = excl;
    __syncthreads();
    for (int i = s0 + t; i < s1; i += 256) {
        int2 e = bdata[i];
        int rl = (e.x >> 20) & 255;
        int pos = atomicAdd(&cur[rl], 1);
        pairs[(size_t)s0 + pos] = make_int2(e.x & 0xFFFFF, e.y);
    }
    if (b == NB - 1 && t == 0) rowptr[N] = E;
}

// ---------------- layer-1 SpMM: wave per row, lane = (edge_group, dim_quad) ----------------
// 16 lanes cover one row (uint2 = 4 bf16 dims each); 4 edge-groups run 4 edges per step,
// unroll x2 => 8 edges in flight per wave. Cross-group reduce via shfl_xor at the end.

__global__ void spmm1_k(const unsigned short* __restrict__ emb16,
                        const int* __restrict__ rowptr, const int2* __restrict__ pairs,
                        int n_total, unsigned short* __restrict__ e1) {
    int wave = (blockIdx.x * blockDim.x + threadIdx.x) >> 6;
    int lane = threadIdx.x & 63;
    if (wave >= n_total) return;
    int eg = lane >> 4, dp = lane & 15;
    int k0 = rowptr[wave], k1 = rowptr[wave + 1];
    float4 a0 = {0.f, 0.f, 0.f, 0.f}, a1 = {0.f, 0.f, 0.f, 0.f};
    for (int k = k0; k < k1; k += 8) {
        int kk0 = k + eg;
        int kk1 = k + 4 + eg;
        int kc0 = kk0 < k1 ? kk0 : k1 - 1;
        int kc1 = kk1 < k1 ? kk1 : k1 - 1;
        int2 p0 = pairs[kc0];
        int2 p1 = pairs[kc1];
        float v0 = kk0 < k1 ? __int_as_float(p0.y) : 0.f;
        float v1 = kk1 < k1 ? __int_as_float(p1.y) : 0.f;
        uint2 g0 = *(const uint2*)(emb16 + (size_t)p0.x * DIM + dp * 4);
        uint2 g1 = *(const uint2*)(emb16 + (size_t)p1.x * DIM + dp * 4);
        float4 x0 = bf2f4(g0);
        float4 x1 = bf2f4(g1);
        a0.x += v0 * x0.x; a0.y += v0 * x0.y; a0.z += v0 * x0.z; a0.w += v0 * x0.w;
        a1.x += v1 * x1.x; a1.y += v1 * x1.y; a1.z += v1 * x1.z; a1.w += v1 * x1.w;
    }
    float4 s;
    s.x = a0.x + a1.x; s.y = a0.y + a1.y; s.z = a0.z + a1.z; s.w = a0.w + a1.w;
    s.x += __shfl_xor(s.x, 16); s.y += __shfl_xor(s.y, 16);
    s.z += __shfl_xor(s.z, 16); s.w += __shfl_xor(s.w, 16);
    s.x += __shfl_xor(s.x, 32); s.y += __shfl_xor(s.y, 32);
    s.z += __shfl_xor(s.z, 32); s.w += __shfl_xor(s.w, 32);
    if (eg == 0) {
        uint2 o;
        o.x = (unsigned)f2bf(s.x) | ((unsigned)f2bf(s.y) << 16);
        o.y = (unsigned)f2bf(s.z) | ((unsigned)f2bf(s.w) << 16);
        *(uint2*)(e1 + (size_t)wave * DIM + dp * 4) = o;
    }
}

// ---------------- fused layer-2 + gather + dot epilogue ----------------

__global__ void final_k(const float* __restrict__ emb_user, const float* __restrict__ emb_item,
                        int n_user, const unsigned short* __restrict__ e1,
                        const int* __restrict__ rowptr, const int2* __restrict__ pairs,
                        const int* __restrict__ u_nodes, const int* __restrict__ p_nodes,
                        const int* __restrict__ n_nodes, int B, float* __restrict__ out) {
    int wave = (blockIdx.x * blockDim.x + threadIdx.x) >> 6;
    int lane = threadIdx.x & 63;
    if (wave >= B) return;
    int eg = lane >> 4, dp = lane & 15;
    int nid[3] = {u_nodes[wave], p_nodes[wave], n_nodes[wave]};
    float4 l[3];
#pragma unroll
    for (int j = 0; j < 3; j++) {
        int r = nid[j];
        const float* base0 = (r < n_user) ? (emb_user + (size_t)r * DIM)
                                          : (emb_item + (size_t)(r - n_user) * DIM);
        float4 acc = *(const float4*)(base0 + dp * 4);                       // layer0 f32
        float4 t1 = bf2f4(*(const uint2*)(e1 + (size_t)r * DIM + dp * 4));   // layer1
        acc.x += t1.x; acc.y += t1.y; acc.z += t1.z; acc.w += t1.w;
        int k0 = rowptr[r], k1 = rowptr[r + 1];
        float4 a0 = {0.f, 0.f, 0.f, 0.f}, a1 = {0.f, 0.f, 0.f, 0.f};
        for (int k = k0; k < k1; k += 8) {
            int kk0 = k + eg;
            int kk1 = k + 4 + eg;
            int kc0 = kk0 < k1 ? kk0 : k1 - 1;
            int kc1 = kk1 < k1 ? kk1 : k1 - 1;
            int2 p0 = pairs[kc0];
            int2 p1 = pairs[kc1];
            float v0 = kk0 < k1 ? __int_as_float(p0.y) : 0.f;
            float v1 = kk1 < k1 ? __int_as_float(p1.y) : 0.f;
            uint2 g0 = *(const uint2*)(e1 + (size_t)p0.x * DIM + dp * 4);
            uint2 g1 = *(const uint2*)(e1 + (size_t)p1.x * DIM + dp * 4);
            float4 x0 = bf2f4(g0);
            float4 x1 = bf2f4(g1);
            a0.x += v0 * x0.x; a0.y += v0 * x0.y; a0.z += v0 * x0.z; a0.w += v0 * x0.w;
            a1.x += v1 * x1.x; a1.y += v1 * x1.y; a1.z += v1 * x1.z; a1.w += v1 * x1.w;
        }
        float4 s;
        s.x = a0.x + a1.x; s.y = a0.y + a1.y; s.z = a0.z + a1.z; s.w = a0.w + a1.w;
        s.x += __shfl_xor(s.x, 16); s.y += __shfl_xor(s.y, 16);
        s.z += __shfl_xor(s.z, 16); s.w += __shfl_xor(s.w, 16);
        s.x += __shfl_xor(s.x, 32); s.y += __shfl_xor(s.y, 32);
        s.z += __shfl_xor(s.z, 32); s.w += __shfl_xor(s.w, 32);
        l[j].x = (acc.x + s.x) * (1.0f / 3.0f);
        l[j].y = (acc.y + s.y) * (1.0f / 3.0f);
        l[j].z = (acc.z + s.z) * (1.0f / 3.0f);
        l[j].w = (acc.w + s.w) * (1.0f / 3.0f);
    }
    float ps = l[0].x * l[1].x + l[0].y * l[1].y + l[0].z * l[1].z + l[0].w * l[1].w;
    float ns = l[0].x * l[2].x + l[0].y * l[2].y + l[0].z * l[2].z + l[0].w * l[2].w;
    ps += __shfl_xor(ps, 1); ns += __shfl_xor(ns, 1);
    ps += __shfl_xor(ps, 2); ns += __shfl_xor(ns, 2);
    ps += __shfl_xor(ps, 4); ns += __shfl_xor(ns, 4);
    ps += __shfl_xor(ps, 8); ns += __shfl_xor(ns, 8);
    if (lane == 0) {
        out[wave] = ps;
        out[B + wave] = ns;
    }
}

extern "C" void kernel_launch(void* const* d_in, const int* in_sizes, int n_in,
                              void* d_out, int out_size, void* d_ws, size_t ws_size,
                              hipStream_t stream) {
    const float* emb_user = (const float*)d_in[0];
    const float* emb_item = (const float*)d_in[1];
    const float* gvals    = (const float*)d_in[2];
    const int*   grow     = (const int*)d_in[3];
    const int*   gcol     = (const int*)d_in[4];
    const int*   unodes   = (const int*)d_in[5];
    const int*   pnodes   = (const int*)d_in[6];
    const int*   nnodes   = (const int*)d_in[7];
    float* out = (float*)d_out;

    int n_user = in_sizes[0] / DIM;
    int n_item = in_sizes[1] / DIM;
    int N = n_user + n_item;
    int E = in_sizes[2];
    int B = in_sizes[5];
    int NB = (N + 255) >> 8;
    int NBLK = (E + CHUNK - 1) / CHUNK;

    char* ws = (char*)d_ws;
    size_t off = 0;
    auto alloc = [&](size_t bytes) -> void* {
        void* p = ws + off;
        off = (off + bytes + 255) & ~(size_t)255;
        return p;
    };
    int*  rowptr      = (int*)alloc((size_t)(N + 1) * 4);
    int*  bucketTotal = (int*)alloc((size_t)MAXNB * 4);
    int*  bucketStart = (int*)alloc((size_t)(MAXNB + 1) * 4);
    int2* pairs       = (int2*)alloc((size_t)E * 8);
    char* regionB = (char*)alloc((size_t)E * 8 > (size_t)N * DIM * 2 ? (size_t)E * 8
                                                                     : (size_t)N * DIM * 2);
    int2*           bdata = (int2*)regionB;
    unsigned short* emb16 = (unsigned short*)regionB;
    size_t countsBytes = (size_t)NBLK * NB * 4;
    size_t e1Bytes = (size_t)N * DIM * 2;
    char* regionA = (char*)alloc(countsBytes > e1Bytes ? countsBytes : e1Bytes);
    int*            counts = (int*)regionA;
    unsigned short* e1     = (unsigned short*)regionA;
    (void)ws_size; (void)n_in; (void)out_size;

    // CSR build via two-level counting sort (no global atomics)
    p1a_hist<<<NBLK, 256, 0, stream>>>(grow, E, NB, counts);
    p1b_scan<<<NB, 256, 0, stream>>>(counts, NBLK, NB, bucketTotal);
    p_scan_tot<<<1, 256, 0, stream>>>(bucketTotal, NB, bucketStart);
    p1c_scatter<<<NBLK, 256, 0, stream>>>(grow, gcol, gvals, E, NB, counts, bucketStart, bdata);
    p2_group<<<NB, 256, 0, stream>>>(bdata, bucketStart, NB, N, E, rowptr, pairs);

    // bf16 pack of embeddings (after P2: emb16 overlays bdata)
    conv_k<<<2048, 256, 0, stream>>>(emb_user, n_user * DIM, emb16);
    conv_k<<<2048, 256, 0, stream>>>(emb_item, n_item * DIM, emb16 + (size_t)n_user * DIM);

    // layer-1 SpMM over all rows (e1 overlays dead counts)
    spmm1_k<<<(N + 3) / 4, 256, 0, stream>>>(emb16, rowptr, pairs, N, e1);
    // fused layer-2 + gather + dots
    final_k<<<(B + 3) / 4, 256, 0, stream>>>(emb_user, emb_item, n_user, e1,
                                             rowptr, pairs,
                                             unodes, pnodes, nnodes, B, out);
}

// Round 5
// 313.908 us; speedup vs baseline: 3.2370x; 1.0202x over previous
//
#include <hip/hip_runtime.h>

#define DIM 64
#define CHUNK 4096    // edges per partition block
#define MAXNB 2048    // max coarse buckets
#define PADSLOP 1792  // max pad entries per bucket (256 rows x 7)
#define P2CAP 7680    // LDS staging capacity (int2) for p2

__device__ __forceinline__ unsigned short f2bf(float f) {
    unsigned int u = __float_as_uint(f);
    return (unsigned short)((u + 0x7FFFu + ((u >> 16) & 1u)) >> 16);  // RNE
}
__device__ __forceinline__ float4 bf2f4(uint2 g) {
    float4 x;
    x.x = __uint_as_float(g.x << 16);
    x.y = __uint_as_float(g.x & 0xffff0000u);
    x.z = __uint_as_float(g.y << 16);
    x.w = __uint_as_float(g.y & 0xffff0000u);
    return x;
}

// inclusive block scan over 256 per-thread values; sh[255] = total after call
__device__ __forceinline__ int blockScan256(int v, int* sh) {
    int t = threadIdx.x;
    sh[t] = v;
    __syncthreads();
    for (int off = 1; off < 256; off <<= 1) {
        int x = (t >= off) ? sh[t - off] : 0;
        __syncthreads();
        sh[t] += x;
        __syncthreads();
    }
    return sh[t];
}

// ---------------- f32 -> packed bf16 conversion (both tables, one launch) ----------------

__global__ void conv2_k(const float* __restrict__ u, const float* __restrict__ it,
                        int nu, int ntot, unsigned short* __restrict__ o) {
    int i = blockIdx.x * blockDim.x + threadIdx.x;
    int stride = gridDim.x * blockDim.x;
    int n8 = ntot >> 3;  // ntot divisible by 8 (DIM=64)
    for (int t = i; t < n8; t += stride) {
        int e = t * 8;
        const float* src = (e < nu) ? (u + e) : (it + (e - nu));
        float4 x = *(const float4*)src;
        float4 y = *(const float4*)(src + 4);
        uint4 v;
        v.x = (unsigned)f2bf(x.x) | ((unsigned)f2bf(x.y) << 16);
        v.y = (unsigned)f2bf(x.z) | ((unsigned)f2bf(x.w) << 16);
        v.z = (unsigned)f2bf(y.x) | ((unsigned)f2bf(y.y) << 16);
        v.w = (unsigned)f2bf(y.z) | ((unsigned)f2bf(y.w) << 16);
        ((uint4*)o)[t] = v;
    }
}

// ---------------- two-level counting sort (no global atomics) ----------------

__global__ void p1a_hist(const int* __restrict__ row, int E, int NB,
                         int* __restrict__ counts) {
    __shared__ int h[MAXNB];
    for (int b = threadIdx.x; b < NB; b += 256) h[b] = 0;
    __syncthreads();
    int base = blockIdx.x * CHUNK;
    int end = min(base + CHUNK, E);
    int vend = base + ((end - base) & ~3);
    for (int i = base + threadIdx.x * 4; i < vend; i += 1024) {
        int4 r = *(const int4*)(row + i);
        atomicAdd(&h[r.x >> 8], 1);
        atomicAdd(&h[r.y >> 8], 1);
        atomicAdd(&h[r.z >> 8], 1);
        atomicAdd(&h[r.w >> 8], 1);
    }
    for (int i = vend + threadIdx.x; i < end; i += 256) atomicAdd(&h[row[i] >> 8], 1);
    __syncthreads();
    int blk = blockIdx.x;
    for (int b = threadIdx.x; b < NB; b += 256) counts[(size_t)blk * NB + b] = h[b];
}

__global__ void p1b_scan(int* __restrict__ counts, int NBLK, int NB,
                         int* __restrict__ bucketTotal) {
    int b = blockIdx.x, t = threadIdx.x;
    __shared__ int sh[256];
    int v[8];
    int run = 0;
#pragma unroll
    for (int i = 0; i < 8; i++) {
        int idx = t * 8 + i;
        int c = (idx < NBLK) ? counts[(size_t)idx * NB + b] : 0;
        v[i] = run;  // exclusive within thread
        run += c;
    }
    int inc = blockScan256(run, sh);
    int excl = inc - run;
#pragma unroll
    for (int i = 0; i < 8; i++) {
        int idx = t * 8 + i;
        if (idx < NBLK) counts[(size_t)idx * NB + b] = v[i] + excl;
    }
    if (t == 255) bucketTotal[b] = sh[255];
}

__global__ void p_scan_tot(const int* __restrict__ bucketTotal, int NB,
                           int* __restrict__ bucketStart) {
    int t = threadIdx.x;
    __shared__ int sh[256];
    int v[8];
    int run = 0;
#pragma unroll
    for (int i = 0; i < 8; i++) {
        int idx = t * 8 + i;
        int c = (idx < NB) ? bucketTotal[idx] : 0;
        v[i] = run;
        run += c;
    }
    int inc = blockScan256(run, sh);
    int excl = inc - run;
#pragma unroll
    for (int i = 0; i < 8; i++) {
        int idx = t * 8 + i;
        if (idx < NB) bucketStart[idx] = v[i] + excl;
    }
    if (t == 255) bucketStart[NB] = sh[255];
}

__global__ void p1c_scatter(const int* __restrict__ row, const int* __restrict__ col,
                            const float* __restrict__ vals, int E, int NB,
                            const int* __restrict__ counts, const int* __restrict__ bucketStart,
                            int2* __restrict__ bdata) {
    __shared__ int cur[MAXNB];
    int blk = blockIdx.x;
    for (int b = threadIdx.x; b < NB; b += 256)
        cur[b] = bucketStart[b] + counts[(size_t)blk * NB + b];
    __syncthreads();
    int base = blk * CHUNK;
    int end = min(base + CHUNK, E);
    int vend = base + ((end - base) & ~3);
    for (int i = base + threadIdx.x * 4; i < vend; i += 1024) {
        int4 r = *(const int4*)(row + i);
        int4 c = *(const int4*)(col + i);
        float4 v = *(const float4*)(vals + i);
        // issue all 4 atomics first (MLP), then the 4 stores
        int p0 = atomicAdd(&cur[r.x >> 8], 1);
        int p1 = atomicAdd(&cur[r.y >> 8], 1);
        int p2 = atomicAdd(&cur[r.z >> 8], 1);
        int p3 = atomicAdd(&cur[r.w >> 8], 1);
        bdata[p0] = make_int2(((r.x & 255) << 20) | c.x, __float_as_int(v.x));
        bdata[p1] = make_int2(((r.y & 255) << 20) | c.y, __float_as_int(v.y));
        bdata[p2] = make_int2(((r.z & 255) << 20) | c.z, __float_as_int(v.z));
        bdata[p3] = make_int2(((r.w & 255) << 20) | c.w, __float_as_int(v.w));
    }
    for (int i = vend + threadIdx.x; i < end; i += 256) {
        int r = row[i];
        int p = atomicAdd(&cur[r >> 8], 1);
        bdata[p] = make_int2(((r & 255) << 20) | col[i], __float_as_int(vals[i]));
    }
}

// P2: per-bucket regroup by exact row into 8-PADDED rows; pads are (colOff=0, val=0).
// pairs.x stores col*128 (byte offset into bf16 row table). LDS-staged, coalesced out.
__global__ void p2_group(const int2* __restrict__ bdata, const int* __restrict__ bucketStart,
                         int NB, int N,
                         int* __restrict__ rowStart, int* __restrict__ rowLen,
                         int2* __restrict__ pairs) {
    __shared__ int hist[256];
    __shared__ int sh[256];
    __shared__ int cur[256];
    __shared__ int2 stage[P2CAP];
    int b = blockIdx.x, t = threadIdx.x;
    int s0 = bucketStart[b], s1 = bucketStart[b + 1];
    int pbase = s0 + b * PADSLOP;  // padded bucket start (deterministic slop)
    hist[t] = 0;
    __syncthreads();
    for (int i = s0 + t; i < s1; i += 256)
        atomicAdd(&hist[(bdata[i].x >> 20) & 255], 1);
    __syncthreads();
    int h = hist[t];
    int hp = (h + 7) & ~7;  // padded row length
    int inc = blockScan256(hp, sh);
    int excl = inc - hp;
    int ptot = sh[255];  // padded bucket total
    int r = b * 256 + t;
    if (r < N) {
        rowStart[r] = pbase + excl;
        rowLen[r] = hp;
    }
    cur[t] = excl;
    __syncthreads();
    if (ptot <= P2CAP) {
        for (int i = t; i < ptot; i += 256) stage[i] = make_int2(0, 0);
        __syncthreads();
        for (int i = s0 + t; i < s1; i += 256) {
            int2 e = bdata[i];
            int rl = (e.x >> 20) & 255;
            int pos = atomicAdd(&cur[rl], 1);
            stage[pos] = make_int2((e.x & 0xFFFFF) << 7, e.y);
        }
        __syncthreads();
        for (int i = t; i < ptot; i += 256) pairs[pbase + i] = stage[i];
    } else {
        // fallback (statistically never for random rows): direct global writes
        for (int i = t; i < ptot; i += 256) pairs[pbase + i] = make_int2(0, 0);
        __syncthreads();  // drains vmem before scatter
        for (int i = s0 + t; i < s1; i += 256) {
            int2 e = bdata[i];
            int rl = (e.x >> 20) & 255;
            int pos = atomicAdd(&cur[rl], 1);
            pairs[pbase + pos] = make_int2((e.x & 0xFFFFF) << 7, e.y);
        }
    }
}

// ---------------- layer-1 SpMM: wave per row, bounds-free padded loop ----------------

__global__ void spmm1_k(const unsigned short* __restrict__ emb16,
                        const int* __restrict__ rowStart, const int* __restrict__ rowLen,
                        const int2* __restrict__ pairs,
                        int n_total, unsigned short* __restrict__ e1) {
    int wave = (blockIdx.x * blockDim.x + threadIdx.x) >> 6;
    int lane = threadIdx.x & 63;
    if (wave >= n_total) return;
    int eg = lane >> 4, dp = lane & 15;
    unsigned off0 = dp * 8u;
    const char* base = (const char*)emb16;
    int len = rowLen[wave];
    const int2* pp = pairs + rowStart[wave];
    float4 a0 = {0.f, 0.f, 0.f, 0.f}, a1 = {0.f, 0.f, 0.f, 0.f};
    for (int k = 0; k < len; k += 8) {
        int2 p0 = pp[k + eg];
        int2 p1 = pp[k + 4 + eg];
        uint2 g0 = *(const uint2*)(base + ((unsigned)p0.x + off0));
        uint2 g1 = *(const uint2*)(base + ((unsigned)p1.x + off0));
        float v0 = __int_as_float(p0.y);
        float v1 = __int_as_float(p1.y);
        float4 x0 = bf2f4(g0);
        float4 x1 = bf2f4(g1);
        a0.x += v0 * x0.x; a0.y += v0 * x0.y; a0.z += v0 * x0.z; a0.w += v0 * x0.w;
        a1.x += v1 * x1.x; a1.y += v1 * x1.y; a1.z += v1 * x1.z; a1.w += v1 * x1.w;
    }
    float4 s;
    s.x = a0.x + a1.x; s.y = a0.y + a1.y; s.z = a0.z + a1.z; s.w = a0.w + a1.w;
    s.x += __shfl_xor(s.x, 16); s.y += __shfl_xor(s.y, 16);
    s.z += __shfl_xor(s.z, 16); s.w += __shfl_xor(s.w, 16);
    s.x += __shfl_xor(s.x, 32); s.y += __shfl_xor(s.y, 32);
    s.z += __shfl_xor(s.z, 32); s.w += __shfl_xor(s.w, 32);
    if (eg == 0) {
        uint2 o;
        o.x = (unsigned)f2bf(s.x) | ((unsigned)f2bf(s.y) << 16);
        o.y = (unsigned)f2bf(s.z) | ((unsigned)f2bf(s.w) << 16);
        *(uint2*)(e1 + (size_t)wave * DIM + dp * 4) = o;
    }
}

// ---------------- fused layer-2 + gather + dot epilogue ----------------

__global__ void final_k(const float* __restrict__ emb_user, const float* __restrict__ emb_item,
                        int n_user, const unsigned short* __restrict__ e1,
                        const int* __restrict__ rowStart, const int* __restrict__ rowLen,
                        const int2* __restrict__ pairs,
                        const int* __restrict__ u_nodes, const int* __restrict__ p_nodes,
                        const int* __restrict__ n_nodes, int B, float* __restrict__ out) {
    int wave = (blockIdx.x * blockDim.x + threadIdx.x) >> 6;
    int lane = threadIdx.x & 63;
    if (wave >= B) return;
    int eg = lane >> 4, dp = lane & 15;
    unsigned off0 = dp * 8u;
    const char* base = (const char*)e1;
    int nid[3] = {u_nodes[wave], p_nodes[wave], n_nodes[wave]};
    float4 l[3];
#pragma unroll
    for (int j = 0; j < 3; j++) {
        int r = nid[j];
        const float* base0 = (r < n_user) ? (emb_user + (size_t)r * DIM)
                                          : (emb_item + (size_t)(r - n_user) * DIM);
        float4 acc = *(const float4*)(base0 + dp * 4);                       // layer0 f32
        float4 t1 = bf2f4(*(const uint2*)(e1 + (size_t)r * DIM + dp * 4));   // layer1
        acc.x += t1.x; acc.y += t1.y; acc.z += t1.z; acc.w += t1.w;
        int len = rowLen[r];
        const int2* pp = pairs + rowStart[r];
        float4 a0 = {0.f, 0.f, 0.f, 0.f}, a1 = {0.f, 0.f, 0.f, 0.f};
        for (int k = 0; k < len; k += 8) {
            int2 p0 = pp[k + eg];
            int2 p1 = pp[k + 4 + eg];
            uint2 g0 = *(const uint2*)(base + ((unsigned)p0.x + off0));
            uint2 g1 = *(const uint2*)(base + ((unsigned)p1.x + off0));
            float v0 = __int_as_float(p0.y);
            float v1 = __int_as_float(p1.y);
            float4 x0 = bf2f4(g0);
            float4 x1 = bf2f4(g1);
            a0.x += v0 * x0.x; a0.y += v0 * x0.y; a0.z += v0 * x0.z; a0.w += v0 * x0.w;
            a1.x += v1 * x1.x; a1.y += v1 * x1.y; a1.z += v1 * x1.z; a1.w += v1 * x1.w;
        }
        float4 s;
        s.x = a0.x + a1.x; s.y = a0.y + a1.y; s.z = a0.z + a1.z; s.w = a0.w + a1.w;
        s.x += __shfl_xor(s.x, 16); s.y += __shfl_xor(s.y, 16);
        s.z += __shfl_xor(s.z, 16); s.w += __shfl_xor(s.w, 16);
        s.x += __shfl_xor(s.x, 32); s.y += __shfl_xor(s.y, 32);
        s.z += __shfl_xor(s.z, 32); s.w += __shfl_xor(s.w, 32);
        l[j].x = (acc.x + s.x) * (1.0f / 3.0f);
        l[j].y = (acc.y + s.y) * (1.0f / 3.0f);
        l[j].z = (acc.z + s.z) * (1.0f / 3.0f);
        l[j].w = (acc.w + s.w) * (1.0f / 3.0f);
    }
    float ps = l[0].x * l[1].x + l[0].y * l[1].y + l[0].z * l[1].z + l[0].w * l[1].w;
    float ns = l[0].x * l[2].x + l[0].y * l[2].y + l[0].z * l[2].z + l[0].w * l[2].w;
    ps += __shfl_xor(ps, 1); ns += __shfl_xor(ns, 1);
    ps += __shfl_xor(ps, 2); ns += __shfl_xor(ns, 2);
    ps += __shfl_xor(ps, 4); ns += __shfl_xor(ns, 4);
    ps += __shfl_xor(ps, 8); ns += __shfl_xor(ns, 8);
    if (lane == 0) {
        out[wave] = ps;
        out[B + wave] = ns;
    }
}

extern "C" void kernel_launch(void* const* d_in, const int* in_sizes, int n_in,
                              void* d_out, int out_size, void* d_ws, size_t ws_size,
                              hipStream_t stream) {
    const float* emb_user = (const float*)d_in[0];
    const float* emb_item = (const float*)d_in[1];
    const float* gvals    = (const float*)d_in[2];
    const int*   grow     = (const int*)d_in[3];
    const int*   gcol     = (const int*)d_in[4];
    const int*   unodes   = (const int*)d_in[5];
    const int*   pnodes   = (const int*)d_in[6];
    const int*   nnodes   = (const int*)d_in[7];
    float* out = (float*)d_out;

    int n_user = in_sizes[0] / DIM;
    int n_item = in_sizes[1] / DIM;
    int N = n_user + n_item;
    int E = in_sizes[2];
    int B = in_sizes[5];
    int NB = (N + 255) >> 8;
    int NBLK = (E + CHUNK - 1) / CHUNK;

    char* ws = (char*)d_ws;
    size_t off = 0;
    auto alloc = [&](size_t bytes) -> void* {
        void* p = ws + off;
        off = (off + bytes + 255) & ~(size_t)255;
        return p;
    };
    int*  rowStart    = (int*)alloc((size_t)N * 4);
    int*  rowLen      = (int*)alloc((size_t)N * 4);
    int*  bucketTotal = (int*)alloc((size_t)MAXNB * 4);
    int*  bucketStart = (int*)alloc((size_t)(MAXNB + 1) * 4);
    int2* pairs       = (int2*)alloc(((size_t)E + (size_t)NB * PADSLOP) * 8);  // padded
    char* regionB = (char*)alloc((size_t)E * 8 > (size_t)N * DIM * 2 ? (size_t)E * 8
                                                                     : (size_t)N * DIM * 2);
    int2*           bdata = (int2*)regionB;
    unsigned short* emb16 = (unsigned short*)regionB;
    size_t countsBytes = (size_t)NBLK * NB * 4;
    size_t e1Bytes = (size_t)N * DIM * 2;
    char* regionA = (char*)alloc(countsBytes > e1Bytes ? countsBytes : e1Bytes);
    int*            counts = (int*)regionA;
    unsigned short* e1     = (unsigned short*)regionA;
    (void)ws_size; (void)n_in; (void)out_size;

    // CSR build via two-level counting sort (no global atomics)
    p1a_hist<<<NBLK, 256, 0, stream>>>(grow, E, NB, counts);
    p1b_scan<<<NB, 256, 0, stream>>>(counts, NBLK, NB, bucketTotal);
    p_scan_tot<<<1, 256, 0, stream>>>(bucketTotal, NB, bucketStart);
    p1c_scatter<<<NBLK, 256, 0, stream>>>(grow, gcol, gvals, E, NB, counts, bucketStart, bdata);
    p2_group<<<NB, 256, 0, stream>>>(bdata, bucketStart, NB, N, rowStart, rowLen, pairs);

    // bf16 pack of embeddings (after p2: emb16 overlays dead bdata)
    conv2_k<<<2048, 256, 0, stream>>>(emb_user, emb_item, n_user * DIM, N * DIM, emb16);

    // layer-1 SpMM over all rows (e1 overlays dead counts)
    spmm1_k<<<(N + 3) / 4, 256, 0, stream>>>(emb16, rowStart, rowLen, pairs, N, e1);
    // fused layer-2 + gather + dots
    final_k<<<(B + 3) / 4, 256, 0, stream>>>(emb_user, emb_item, n_user, e1,
                                             rowStart, rowLen, pairs,
                                             unodes, pnodes, nnodes, B, out);
}